// Round 1
// baseline (5481.469 us; speedup 1.0000x reference)
//
#include <hip/hip_runtime.h>
#include <cstdint>
#include <cstddef>

// LSTM decoder, B=256, H=1024, T=128 (seq len fixed by setup_inputs).
// Strategy: bf16 MFMA with 3-pass hi/lo split (~fp32 accuracy):
//   h@W ~= h1@W1 + h2@W1 + h1@W2   (h=h1+h2, W=W1+W2 in bf16)
// x-projections + both biases folded into xpre once; 128 per-step kernels.

#define DI __device__ __forceinline__

typedef __attribute__((ext_vector_type(8))) short   short8;
typedef __attribute__((ext_vector_type(4))) float   f32x4;
typedef __attribute__((ext_vector_type(4))) unsigned short u16x4;
typedef unsigned short u16;
typedef unsigned int   u32;

static constexpr int H = 1024;
static constexpr int B = 256;
static constexpr int T = 128;   // expected_seq_len from setup_inputs

DI u16 f2bf(float f){
  union { float f; u32 u; } v; v.f = f;
  u32 r = v.u + 0x7fffu + ((v.u >> 16) & 1u);   // RNE (no NaN in this data)
  return (u16)(r >> 16);
}
DI float bf2f(u16 h){
  union { u32 u; float f; } v; v.u = ((u32)h) << 16; return v.f;
}
DI float sigf(float z){ return 1.0f / (1.0f + __expf(-z)); }
DI float tanh_(float z){
  float e = __expf(-2.0f * fabsf(z));
  float t = (1.0f - e) / (1.0f + e);
  return z < 0.0f ? -t : t;
}

// ---------------- prep: fp32 -> bf16 hi/lo planes ----------------
struct PrepParams {
  const float* srcW[8];   // 0..3: W_h{i,f,o,c}; 4..7: W_x{i,f,o,c}
  const float* x;
  u16* Wh1; u16* Wh2; u16* Wx1; u16* Wx2; u16* x1; u16* x2;
};

__global__ __launch_bounds__(256) void prep_kernel(PrepParams p){
  const int WUNITS = 8 * (H * H / 4);            // float4 units over 8 matrices
  int u = blockIdx.x * 256 + threadIdx.x;
  if (u < WUNITS){
    int m   = u >> 18;                           // H*H/4 = 2^18 units/matrix
    int off = (u & ((1 << 18) - 1)) * 4;
    f32x4 v = *(const f32x4*)(p.srcW[m] + off);
    u16x4 hi, lo;
    #pragma unroll
    for (int i = 0; i < 4; ++i){
      u16 h = f2bf(v[i]);
      hi[i] = h;
      lo[i] = f2bf(v[i] - bf2f(h));
    }
    u16 *dhi, *dlo;
    if (m < 4){ dhi = p.Wh1 + (m << 20) + off;       dlo = p.Wh2 + (m << 20) + off; }
    else      { dhi = p.Wx1 + ((m - 4) << 20) + off; dlo = p.Wx2 + ((m - 4) << 20) + off; }
    *(u16x4*)dhi = hi;
    *(u16x4*)dlo = lo;
  } else {
    int idx = u - WUNITS;                        // B*H/4 = 65536 units
    int off = idx * 4;
    f32x4 v = *(const f32x4*)(p.x + off);
    u16x4 hi, lo;
    #pragma unroll
    for (int i = 0; i < 4; ++i){
      u16 h = f2bf(v[i]);
      hi[i] = h;
      lo[i] = f2bf(v[i] - bf2f(h));
    }
    *(u16x4*)(p.x1 + off) = hi;
    *(u16x4*)(p.x2 + off) = lo;
  }
}

// ---------------- shared GEMM core ----------------
// Per wave: 16 batch rows x 16 cols x 4 gates, K=1024, mfma 16x16x32 bf16.
// A frag (lane l, elem i) = A[l&15][k0 + (l>>4)*8 + i]   (16B contiguous)
// B frag (lane l, elem i) = W[n0+(l&15)][k0 + (l>>4)*8 + i]
// D (lane l, reg j) = out[(l>>4)*4 + j][l&15]
DI void gemm4(const u16* __restrict__ a1p, const u16* __restrict__ a2p,
              const u16* __restrict__ b1p, const u16* __restrict__ b2p,
              f32x4 acc[4]){
  #pragma unroll 2
  for (int k0 = 0; k0 < H; k0 += 32){
    short8 a1 = *(const short8*)(a1p + k0);
    short8 a2 = *(const short8*)(a2p + k0);
    #pragma unroll
    for (int g = 0; g < 4; ++g){
      short8 b1 = *(const short8*)(b1p + (g << 20) + k0);
      short8 b2 = *(const short8*)(b2p + (g << 20) + k0);
      acc[g] = __builtin_amdgcn_mfma_f32_16x16x32_bf16(a1, b1, acc[g], 0, 0, 0);
      acc[g] = __builtin_amdgcn_mfma_f32_16x16x32_bf16(a2, b1, acc[g], 0, 0, 0);
      acc[g] = __builtin_amdgcn_mfma_f32_16x16x32_bf16(a1, b2, acc[g], 0, 0, 0);
    }
  }
}

// ---------------- xpre = x@Wx^T + b_x + b_h ----------------
struct XpreParams {
  const u16* x1; const u16* x2; const u16* Wx1; const u16* Wx2;
  const float* bx[4]; const float* bh[4];
  float* xpre;    // [4][B][H]
};

__global__ __launch_bounds__(256) void xpre_kernel(XpreParams p){
  int lane = threadIdx.x & 63, wv = threadIdx.x >> 6;
  int l15 = lane & 15, lhi = lane >> 4;
  int ng = blockIdx.x & 63, mg = blockIdx.x >> 6;
  int n0 = ng * 16, b0 = mg * 64 + wv * 16;
  int aoff = (b0 + l15) * H + lhi * 8;
  int boff = (n0 + l15) * H + lhi * 8;

  f32x4 acc[4] = {};
  gemm4(p.x1 + aoff, p.x2 + aoff, p.Wx1 + boff, p.Wx2 + boff, acc);

  int col = n0 + l15;
  #pragma unroll
  for (int g = 0; g < 4; ++g){
    float bias = p.bx[g][col] + p.bh[g][col];
    #pragma unroll
    for (int j = 0; j < 4; ++j){
      int row = b0 + lhi * 4 + j;
      p.xpre[(size_t)g * B * H + (size_t)row * H + col] = acc[g][j] + bias;
    }
  }
}

// ---------------- one recurrent step ----------------
struct StepParams {
  const u16* Wh1; const u16* Wh2;
  u16* hb;            // [2 parity][2 plane][B][H] bf16 bits
  const float* xpre;  // [4][B][H]
  float* c;           // [B][H]
  float* out;         // [B][T][H]
};

__global__ __launch_bounds__(256) void step_kernel(StepParams p, int t){
  int lane = threadIdx.x & 63, wv = threadIdx.x >> 6;
  int l15 = lane & 15, lhi = lane >> 4;
  int ng = blockIdx.x & 63, mg = blockIdx.x >> 6;
  int n0 = ng * 16, b0 = mg * 64 + wv * 16;
  int aoff = (b0 + l15) * H + lhi * 8;
  int boff = (n0 + l15) * H + lhi * 8;

  f32x4 acc[4] = {};
  if (t > 0){
    const u16* Hb = p.hb + (size_t)(t & 1) * (2 * B * H);
    gemm4(Hb + aoff, Hb + B * H + aoff, p.Wh1 + boff, p.Wh2 + boff, acc);
  }

  int col = n0 + l15;
  u16* HBo = p.hb + (size_t)((t + 1) & 1) * (2 * B * H);
  #pragma unroll
  for (int j = 0; j < 4; ++j){
    int row = b0 + lhi * 4 + j;
    size_t rc = (size_t)row * H + col;
    float pi = p.xpre[0 * B * H + rc] + acc[0][j];
    float pf = p.xpre[1 * B * H + rc] + acc[1][j];
    float po = p.xpre[2 * B * H + rc] + acc[2][j];
    float pc = p.xpre[3 * B * H + rc] + acc[3][j];
    float ig = sigf(pi), fg = sigf(pf), og = sigf(po), gg = tanh_(pc);
    float cprev = (t > 0) ? p.c[rc] : 0.0f;
    float cn = fg * cprev + ig * gg;
    p.c[rc] = cn;
    float h = og * tanh_(cn);
    p.out[(size_t)row * T * H + (size_t)t * H + col] = h;
    u16 h1 = f2bf(h);
    u16 h2 = f2bf(h - bf2f(h1));
    HBo[rc] = h1;
    HBo[B * H + rc] = h2;
  }
}

// ---------------- launch ----------------
extern "C" void kernel_launch(void* const* d_in, const int* in_sizes, int n_in,
                              void* d_out, int out_size, void* d_ws, size_t ws_size,
                              hipStream_t stream){
  (void)in_sizes; (void)n_in; (void)out_size; (void)ws_size;
  const float* x    = (const float*)d_in[0];
  const float* W_xi = (const float*)d_in[1];  const float* b_xi = (const float*)d_in[2];
  const float* W_hi = (const float*)d_in[3];  const float* b_hi = (const float*)d_in[4];
  const float* W_xf = (const float*)d_in[5];  const float* b_xf = (const float*)d_in[6];
  const float* W_hf = (const float*)d_in[7];  const float* b_hf = (const float*)d_in[8];
  const float* W_xo = (const float*)d_in[9];  const float* b_xo = (const float*)d_in[10];
  const float* W_ho = (const float*)d_in[11]; const float* b_ho = (const float*)d_in[12];
  const float* W_xc = (const float*)d_in[13]; const float* b_xc = (const float*)d_in[14];
  const float* W_hc = (const float*)d_in[15]; const float* b_hc = (const float*)d_in[16];
  float* out = (float*)d_out;

  // ws carve (all element counts keep 16B alignment). Total ~41.7 MB.
  const size_t M1 = (size_t)4 << 20;          // elements per 4-gate plane set
  u16* ws  = (u16*)d_ws;
  u16* Wh1 = ws;
  u16* Wh2 = Wh1 + M1;
  u16* Wx1 = Wh2 + M1;
  u16* Wx2 = Wx1 + M1;
  u16* x1  = Wx2 + M1;
  u16* x2  = x1 + (size_t)B * H;
  u16* hb  = x2 + (size_t)B * H;              // 4*B*H u16
  float* xpre = (float*)(hb + (size_t)4 * B * H);  // 4*B*H f32
  float* cbuf = xpre + (size_t)4 * B * H;          // B*H f32

  PrepParams pp;
  pp.srcW[0] = W_hi; pp.srcW[1] = W_hf; pp.srcW[2] = W_ho; pp.srcW[3] = W_hc;
  pp.srcW[4] = W_xi; pp.srcW[5] = W_xf; pp.srcW[6] = W_xo; pp.srcW[7] = W_xc;
  pp.x = x; pp.Wh1 = Wh1; pp.Wh2 = Wh2; pp.Wx1 = Wx1; pp.Wx2 = Wx2;
  pp.x1 = x1; pp.x2 = x2;
  prep_kernel<<<8448, 256, 0, stream>>>(pp);

  XpreParams xp;
  xp.x1 = x1; xp.x2 = x2; xp.Wx1 = Wx1; xp.Wx2 = Wx2;
  xp.bx[0] = b_xi; xp.bx[1] = b_xf; xp.bx[2] = b_xo; xp.bx[3] = b_xc;
  xp.bh[0] = b_hi; xp.bh[1] = b_hf; xp.bh[2] = b_ho; xp.bh[3] = b_hc;
  xp.xpre = xpre;
  xpre_kernel<<<256, 256, 0, stream>>>(xp);

  StepParams sp;
  sp.Wh1 = Wh1; sp.Wh2 = Wh2; sp.hb = hb; sp.xpre = xpre; sp.c = cbuf; sp.out = out;
  for (int t = 0; t < T; ++t)
    step_kernel<<<256, 256, 0, stream>>>(sp, t);
}